// Round 3
// baseline (237.642 us; speedup 1.0000x reference)
//
#include <hip/hip_runtime.h>

// Problem constants (fixed by the reference)
constexpr int C_ = 2048;
constexpr int H_ = 16;
constexpr int W_ = 16;
constexpr int F_ = 64;
constexpr int P_ = 256;                 // samples per complex
constexpr int MAP4 = H_ * W_ * F_ / 4;  // 4096 float4 = 64 KB
constexpr int BLK = 1024;               // 16 waves per block
constexpr int ITERS = P_ / (BLK / 16);  // 4 phase-2 iterations

// Round-2 lesson: occupancy (32 waves/CU) alone didn't help because
// __launch_bounds__(1024,8) let the compiler shrink to 16 VGPRs -> zero ILP:
// the stage serialized into 4x (global_load -> vmcnt(0) -> ds_write), ~4 HBM
// latencies per wave, and phase-2 serialized its ds_reads. Fix the latency
// chains, keep the TLP:
//  - stage with global_load_lds width=16 (fire-and-forget DMA, no VGPR trip,
//    all 4 chunks in flight, ONE drain at the barrier)
//  - batch all phase-2 coeffs into registers up front (static indexing)
typedef __attribute__((address_space(3))) uint32_t lds_u32;
typedef const __attribute__((address_space(1))) uint32_t glb_u32;

__global__ __launch_bounds__(BLK, 8) void ngf_fetch_kernel(
    const float* __restrict__ map_,
    const float* __restrict__ u_,
    const float* __restrict__ v_,
    float* __restrict__ out_) {
  __shared__ float4 smap[MAP4];   // 64 KB: map[c] as [H][W][F/4] float4
  __shared__ float4 s_w[P_];      // (w00, w01, w10, w11) per sample
  __shared__ int    s_ix[P_];     // (y0*W + x0) * (F/4), in float4 units

  const int c = blockIdx.x;
  const int tid = threadIdx.x;

  // ---- async stage: 4096 float4 / 1024 threads = 4 chunks, all in flight ----
  // Wave-uniform LDS base + lane*16 holds: chunk base = i*1024 + wave*64,
  // lane l writes element (base + l) at LDS offset (base + l)*16. Linear. OK.
  const float4* __restrict__ gmap =
      (const float4*)(map_ + (size_t)c * (H_ * W_ * F_));
#pragma unroll
  for (int i = 0; i < MAP4 / BLK; ++i) {
    __builtin_amdgcn_global_load_lds((glb_u32*)(gmap + i * BLK + tid),
                                     (lds_u32*)(smap + i * BLK + tid),
                                     16, 0, 0);
  }

  // ---- per-sample coefficients (first 4 waves; one sample per thread) ----
  // Runs while the DMA is in flight.
  if (tid < P_) {
    const float x = u_[(size_t)c * P_ + tid] * (float)(W_ - 1);
    const float y = v_[(size_t)c * P_ + tid] * (float)(H_ - 1);
    int x0 = (int)floorf(x);
    int y0 = (int)floorf(y);
    x0 = x0 < 0 ? 0 : (x0 > W_ - 2 ? W_ - 2 : x0);
    y0 = y0 < 0 ? 0 : (y0 > H_ - 2 ? H_ - 2 : y0);
    const float fx = x - (float)x0;
    const float fy = y - (float)y0;
    const float wx0 = 1.0f - fx;
    const float wy0 = 1.0f - fy;
    s_w[tid] = make_float4(wx0 * wy0, fx * wy0, wx0 * fy, fx * fy);
    s_ix[tid] = (y0 * W_ + x0) * (F_ / 4);
  }
  __syncthreads();   // drains vmcnt (DMA) + lgkmcnt once

  // ---- gather from LDS + weighted sum + store ----
  float4* __restrict__ gout = (float4*)(out_ + (size_t)c * (P_ * F_));
  const int f = tid & 15;        // float4 index along feature dim (0..15)
  const int sbase = tid >> 4;    // 0..63

  // Batch all per-iteration coeffs into registers first (static indexing ->
  // stays in VGPRs; forces enough live state that the allocator gives us ILP).
  float4 w[ITERS];
  int ix[ITERS];
#pragma unroll
  for (int it = 0; it < ITERS; ++it) {
    const int s = it * (BLK / 16) + sbase;
    w[it] = s_w[s];
    ix[it] = s_ix[s] + f;
  }

#pragma unroll
  for (int it = 0; it < ITERS; ++it) {
    const int s = it * (BLK / 16) + sbase;
    const float4 g00 = smap[ix[it]];
    const float4 g01 = smap[ix[it] + (F_ / 4)];            // x0+1
    const float4 g10 = smap[ix[it] + W_ * (F_ / 4)];       // y0+1
    const float4 g11 = smap[ix[it] + (W_ + 1) * (F_ / 4)]; // y0+1, x0+1

    float4 r;
    r.x = g00.x * w[it].x + g01.x * w[it].y + g10.x * w[it].z + g11.x * w[it].w;
    r.y = g00.y * w[it].x + g01.y * w[it].y + g10.y * w[it].z + g11.y * w[it].w;
    r.z = g00.z * w[it].x + g01.z * w[it].y + g10.z * w[it].z + g11.z * w[it].w;
    r.w = g00.w * w[it].x + g01.w * w[it].y + g10.w * w[it].z + g11.w * w[it].w;

    gout[s * (F_ / 4) + f] = r;   // wave writes 1 KB contiguous
  }
}

extern "C" void kernel_launch(void* const* d_in, const int* in_sizes, int n_in,
                              void* d_out, int out_size, void* d_ws, size_t ws_size,
                              hipStream_t stream) {
  const float* map_ = (const float*)d_in[0];
  const float* u_   = (const float*)d_in[1];
  const float* v_   = (const float*)d_in[2];
  float* out_ = (float*)d_out;

  ngf_fetch_kernel<<<C_, BLK, 0, stream>>>(map_, u_, v_, out_);
}